// Round 1
// baseline (166.864 us; speedup 1.0000x reference)
//
#include <hip/hip_runtime.h>

#define N_DIM   3072
#define BATCH_N 8192
#define K_FIX   30

// ---------------- Path 1: specialized fast kernel (diag_pos[i] == i) --------
// Each thread computes RT=4 consecutive output columns r in [R0, R0+4) and
// slides over batch rows. x window (36 floats) lives in registers with static
// indices; V fragment (30x4) hoisted out of the b-loop.
#define RT       4
#define RBLOCK   (256 * RT)          // 1024 r per block
#define NR_CHUNK (N_DIM / RBLOCK)    // 3
#define NBT      512
#define BROWS    (BATCH_N / NBT)     // 16 batch rows per block

__global__ __launch_bounds__(256)
void fc_diag_fast(const float* __restrict__ x, const float* __restrict__ V,
                  const int* __restrict__ dp, float* __restrict__ out)
{
    // Wave-uniform pattern check: proceed only if diag_pos == 0..29.
    bool ok = true;
    #pragma unroll
    for (int i = 0; i < K_FIX; ++i) ok = ok && (dp[i] == i);
    if (!ok) return;

    const int rchunk = blockIdx.x % NR_CHUNK;
    const int btile  = blockIdx.x / NR_CHUNK;
    const int R0 = rchunk * RBLOCK + (int)threadIdx.x * RT;
    const int b0 = btile * BROWS;

    // VW[i][j] = V[i, (R0 + j - i) mod N] -- reused across all batch rows.
    float VW[K_FIX][RT];
    #pragma unroll
    for (int i = 0; i < K_FIX; ++i) {
        #pragma unroll
        for (int j = 0; j < RT; ++j) {
            int c = R0 + j - i;
            if (c < 0) c += N_DIM;
            VW[i][j] = V[(size_t)i * N_DIM + c];
        }
    }

    const int WL = RT + 32;  // 36-float x window: covers c in [R0-32, R0+4)
    for (int b = b0; b < b0 + BROWS; ++b) {
        const float* xb = x + (size_t)b * N_DIM;
        float XW[WL];
        #pragma unroll
        for (int k = 0; k < WL / 4; ++k) {
            int c0 = R0 - 32 + 4 * k;            // stays 16B-aligned
            if (c0 < 0) c0 += N_DIM;             // N_DIM % 4 == 0: no row-cross
            const float4 v = *reinterpret_cast<const float4*>(xb + c0);
            XW[4*k+0] = v.x; XW[4*k+1] = v.y; XW[4*k+2] = v.z; XW[4*k+3] = v.w;
        }
        float acc[RT] = {0.f, 0.f, 0.f, 0.f};
        #pragma unroll
        for (int i = 0; i < K_FIX; ++i) {
            #pragma unroll
            for (int j = 0; j < RT; ++j) {
                // XW index 32+j-i in [3,35] -- compile-time constant.
                acc[j] = fmaf(XW[32 + j - i], VW[i][j], acc[j]);
            }
        }
        float4 o; o.x = acc[0]; o.y = acc[1]; o.z = acc[2]; o.w = acc[3];
        *reinterpret_cast<float4*>(out + (size_t)b * N_DIM + R0) = o;
    }
}

// ---------------- Path 2: general K=30 (arbitrary diag values) --------------
// One output column r per thread; CI/VW register arrays statically unrolled.
#define G_NBT   128
#define G_BROWS (BATCH_N / G_NBT)    // 64

__global__ __launch_bounds__(256)
void fc_diag_general30(const float* __restrict__ x, const float* __restrict__ V,
                       const int* __restrict__ dp, float* __restrict__ out)
{
    bool contig = true;
    #pragma unroll
    for (int i = 0; i < K_FIX; ++i) contig = contig && (dp[i] == i);
    if (contig) return;  // fast kernel handled it

    const int NRT = N_DIM / 256;     // 12 r-tiles
    const int rtile = blockIdx.x % NRT;
    const int btile = blockIdx.x / NRT;
    const int r  = rtile * 256 + (int)threadIdx.x;
    const int b0 = btile * G_BROWS;

    int   CI[K_FIX];
    float VW[K_FIX];
    #pragma unroll
    for (int i = 0; i < K_FIX; ++i) {
        int d = dp[i] % N_DIM; if (d < 0) d += N_DIM;
        int c = r - d; if (c < 0) c += N_DIM;
        CI[i] = c;
        VW[i] = V[(size_t)d * N_DIM + c];
    }

    for (int b = b0; b < b0 + G_BROWS; b += 2) {
        const float* xb0 = x + (size_t)b * N_DIM;
        const float* xb1 = xb0 + N_DIM;
        float a0 = 0.f, a1 = 0.f;
        #pragma unroll
        for (int i = 0; i < K_FIX; ++i) {
            const float w = VW[i]; const int c = CI[i];
            a0 = fmaf(xb0[c], w, a0);
            a1 = fmaf(xb1[c], w, a1);
        }
        out[(size_t)b * N_DIM + r]       = a0;
        out[(size_t)(b + 1) * N_DIM + r] = a1;
    }
}

// ---------------- Path 3: naive fallback for K != 30 ------------------------
__global__ void fc_diag_naive(const float* __restrict__ x, const float* __restrict__ V,
                              const int* __restrict__ dp, int K, float* __restrict__ out)
{
    size_t idx   = (size_t)blockIdx.x * blockDim.x + threadIdx.x;
    size_t total = (size_t)BATCH_N * N_DIM;
    size_t step  = (size_t)gridDim.x * blockDim.x;
    for (; idx < total; idx += step) {
        int b = (int)(idx / N_DIM), r = (int)(idx % N_DIM);
        float acc = 0.f;
        for (int i = 0; i < K; ++i) {
            int d = dp[i] % N_DIM; if (d < 0) d += N_DIM;
            int c = r - d; if (c < 0) c += N_DIM;
            acc = fmaf(x[(size_t)b * N_DIM + c], V[(size_t)d * N_DIM + c], acc);
        }
        out[idx] = acc;
    }
}

extern "C" void kernel_launch(void* const* d_in, const int* in_sizes, int n_in,
                              void* d_out, int out_size, void* d_ws, size_t ws_size,
                              hipStream_t stream)
{
    const float* x  = (const float*)d_in[0];
    const float* V  = (const float*)d_in[1];
    const int*   dp = (const int*)d_in[2];
    float* out = (float*)d_out;
    const int K = in_sizes[2];

    if (K == K_FIX) {
        fc_diag_fast<<<dim3(NR_CHUNK * NBT), dim3(256), 0, stream>>>(x, V, dp, out);
        fc_diag_general30<<<dim3((N_DIM / 256) * G_NBT), dim3(256), 0, stream>>>(x, V, dp, out);
    } else {
        fc_diag_naive<<<dim3(2048), dim3(256), 0, stream>>>(x, V, dp, K, out);
    }
}